// Round 20
// baseline (99.945 us; speedup 1.0000x reference)
//
#include <hip/hip_runtime.h>
#include <stdint.h>

#define BATCH 2
#define SEQ   2048
#define DIM   1024
#define NH    16
#define HD    64
#define KK    46
#define NSEL  (BATCH*KK)   // 92
#define MPAD  128
#define CHUNK 128
#define NCH   (SEQ/CHUNK)  // 16
#define QP    48           // padded query rows (3 MFMA m-tiles)
#define SPLITK 8

typedef __attribute__((ext_vector_type(8))) short short8;
typedef __attribute__((ext_vector_type(4))) float f32x4;

__device__ inline unsigned short f2bf(float f) {
  union { float f; uint32_t u; } v; v.f = f;
  uint32_t u = v.u;
  uint32_t r = u + 0x7fff + ((u >> 16) & 1);
  return (unsigned short)(r >> 16);
}
__device__ inline float bf2f(unsigned short h) {
  union { uint32_t u; float f; } v; v.u = ((uint32_t)h) << 16;
  return v.f;
}
__device__ inline uint32_t f2ord(float f) {
  union { float f; uint32_t u; } v; v.f = f;
  return (v.u & 0x80000000u) ? ~v.u : (v.u | 0x80000000u);
}

// async global->LDS, 16B per lane; LDS dest = wave-uniform base + lane*16
__device__ inline void gload16(const void* g, void* l) {
  __builtin_amdgcn_global_load_lds(
      (const __attribute__((address_space(1))) void*)g,
      (__attribute__((address_space(3))) void*)l, 16, 0, 0);
}

// Merged prep: blocks 0..2047 convert weights; blocks 2048..3071: x row ->
// bf16 xb + selz dot + out base copy.
__global__ __launch_bounds__(256) void prep_kernel(
    const float* __restrict__ wqkv, const float* __restrict__ outw,
    unsigned short* __restrict__ wqkvb, unsigned short* __restrict__ outwb,
    const float* __restrict__ x, unsigned short* __restrict__ xb,
    const float* __restrict__ sel_w, const float* __restrict__ sel_b,
    float* __restrict__ z, float* __restrict__ out)
{
  if (blockIdx.x < 2048) {
    int i = (blockIdx.x * 256 + threadIdx.x) * 8;
    const int NW = 3 * DIM * DIM;
    const float* src; unsigned short* dst; int j;
    if (i < NW) { src = wqkv; dst = wqkvb; j = i; }
    else        { src = outw; dst = outwb; j = i - NW; }
    float4 a = *(const float4*)(src + j);
    float4 b = *(const float4*)(src + j + 4);
    ushort4 o0, o1;
    o0.x = f2bf(a.x); o0.y = f2bf(a.y); o0.z = f2bf(a.z); o0.w = f2bf(a.w);
    o1.x = f2bf(b.x); o1.y = f2bf(b.y); o1.z = f2bf(b.z); o1.w = f2bf(b.w);
    *(ushort4*)(dst + j)     = o0;
    *(ushort4*)(dst + j + 4) = o1;
  } else {
    int wave = threadIdx.x >> 6, lane = threadIdx.x & 63;
    int row = (blockIdx.x - 2048) * 4 + wave;
    const float* xr = x + (size_t)row * DIM;
    unsigned short* xo = xb + (size_t)row * DIM;
    float* oo = out + (size_t)row * DIM;
    float s = 0.f;
#pragma unroll
    for (int it = 0; it < 4; ++it) {
      int c = it * 256 + lane * 4;
      float4 xv = *(const float4*)(xr + c);
      float4 wv = *(const float4*)(sel_w + c);
      s += xv.x*wv.x + xv.y*wv.y + xv.z*wv.z + xv.w*wv.w;
      ushort4 o;
      o.x = f2bf(xv.x); o.y = f2bf(xv.y); o.z = f2bf(xv.z); o.w = f2bf(xv.w);
      *(ushort4*)(xo + c) = o;
      *(float4*)(oo + c) = xv;
    }
#pragma unroll
    for (int o = 32; o > 0; o >>= 1) s += __shfl_xor(s, o);
    if (lane == 0) z[row] = s + sel_b[0];
  }
}

// Radix-select top-KK + softmax(sel). One block per batch.
__global__ __launch_bounds__(256) void topk_kernel(const float* __restrict__ z,
                                                   float* __restrict__ sel,
                                                   int* __restrict__ idxout)
{
  int b = blockIdx.x, t = threadIdx.x;
  int lane = t & 63, wid = t >> 6;
  __shared__ int   hist[256];
  __shared__ float fred[4];
  __shared__ int   ired[4];
  __shared__ int   s_B, s_need;
  __shared__ float s_mx, s_sum;

  int s0 = t * 8;
  float zz[8];
  uint32_t uu[8];
  {
    float4 a = *(const float4*)(z + b*SEQ + s0);
    float4 c = *(const float4*)(z + b*SEQ + s0 + 4);
    zz[0]=a.x; zz[1]=a.y; zz[2]=a.z; zz[3]=a.w;
    zz[4]=c.x; zz[5]=c.y; zz[6]=c.z; zz[7]=c.w;
  }
#pragma unroll
  for (int i = 0; i < 8; ++i) uu[i] = f2ord(zz[i]);

  float lm = zz[0];
#pragma unroll
  for (int i = 1; i < 8; ++i) lm = fmaxf(lm, zz[i]);
#pragma unroll
  for (int o = 32; o > 0; o >>= 1) lm = fmaxf(lm, __shfl_xor(lm, o));
  if (lane == 0) fred[wid] = lm;
  __syncthreads();
  if (t == 0) s_mx = fmaxf(fmaxf(fred[0], fred[1]), fmaxf(fred[2], fred[3]));
  __syncthreads();
  float mx = s_mx;

  float pp[8];
  float ls = 0.f;
#pragma unroll
  for (int i = 0; i < 8; ++i) { pp[i] = __expf(zz[i] - mx); ls += pp[i]; }
#pragma unroll
  for (int o = 32; o > 0; o >>= 1) ls += __shfl_xor(ls, o);
  if (lane == 0) fred[wid] = ls;
  __syncthreads();
  if (t == 0) s_sum = fred[0] + fred[1] + fred[2] + fred[3];
  __syncthreads();
  float sscale = 4.0f / s_sum;   // sqrt(DIM)/8 = 4
#pragma unroll
  for (int i = 0; i < 8; ++i) sel[b*SEQ + s0 + i] = pp[i] * sscale;

  uint32_t pref = 0;
  int need = KK;
#pragma unroll
  for (int pass = 0; pass < 4; ++pass) {
    int shift = 24 - pass * 8;
    uint32_t maskhi = pass ? (0xFFFFFFFFu << (shift + 8)) : 0u;
    hist[t] = 0;
    __syncthreads();
#pragma unroll
    for (int i = 0; i < 8; ++i) {
      if ((uu[i] & maskhi) == pref)
        atomicAdd(&hist[(uu[i] >> shift) & 255], 1);
    }
    __syncthreads();
    if (t < 64) {
      int c0 = hist[t*4], c1 = hist[t*4+1], c2 = hist[t*4+2], c3 = hist[t*4+3];
      int sl = c0 + c1 + c2 + c3;
      int suf = sl;
#pragma unroll
      for (int off = 1; off < 64; off <<= 1) {
        int o = __shfl_down(suf, off);
        if (lane + off < 64) suf += o;
      }
      int above = suf - sl;
      if (above < need && above + sl >= need) {
        int cum = above;
        int cs[4] = {c0, c1, c2, c3};
#pragma unroll
        for (int k = 3; k >= 0; --k) {
          if (cum < need && cum + cs[k] >= need) {
            s_B = t*4 + k;
            s_need = need - cum;
            break;
          }
          cum += cs[k];
        }
      }
    }
    __syncthreads();
    pref |= ((uint32_t)s_B) << shift;
    need = s_need;
    __syncthreads();
  }
  uint32_t T = pref;

  int cgt = 0, ceq = 0;
#pragma unroll
  for (int i = 0; i < 8; ++i) { cgt += (uu[i] > T); ceq += (uu[i] == T); }
  int pack = (cgt << 12) | ceq;
  int inc = pack;
#pragma unroll
  for (int off = 1; off < 64; off <<= 1) {
    int o = __shfl_up(inc, off);
    if (lane >= off) inc += o;
  }
  if (lane == 63) ired[wid] = inc;
  __syncthreads();
  int wbase = 0;
  if (wid == 1) wbase = ired[0];
  else if (wid == 2) wbase = ired[0] + ired[1];
  else if (wid == 3) wbase = ired[0] + ired[1] + ired[2];
  int ex = wbase + inc - pack;
  int g = ex >> 12, e = ex & 0xFFF;
#pragma unroll
  for (int i = 0; i < 8; ++i) {
    int s = s0 + i;
    bool isgt = uu[i] > T;
    bool iseq = uu[i] == T;
    int rank = -1;
    if (isgt) rank = g + (e < need ? e : need);
    else if (iseq && e < need) rank = g + e;
    if (rank >= 0) idxout[b*KK + rank] = s;
    g += isgt; e += iseq;
  }
}

// Merged GEMM launch: blocks 0..511 = KV projection; 512..575 = Q split-K gather.
// 4 waves, 128x128 tile, XOR-swizzled LDS. 3-buffer depth-2 pipeline:
// raw s_barrier + counted vmcnt(4); stage(t+2) issued post-barrier (WAR-safe).
__global__ __launch_bounds__(256) void gemms_kernel(
    const unsigned short* __restrict__ xb,
    const unsigned short* __restrict__ wqkvb,
    const float* __restrict__ Wqkv_b,
    unsigned short* __restrict__ kvb,
    float* __restrict__ qpart,
    const int* __restrict__ idxp)
{
  __shared__ unsigned short As[3][128*32];
  __shared__ unsigned short Bs[3][128*32];
  int tid  = threadIdx.x;
  int lane = tid & 63, wave = tid >> 6;
  int wr = (wave >> 1) * 64, wc = (wave & 1) * 64;
  int lr = lane & 15;
  int sx = (((lane >> 4) ^ ((lane >> 1) & 3)) << 3);   // swizzled read slot
  int srow = lane >> 2;
  int scol = (((lane & 3) ^ ((lane >> 3) & 3)) << 3);  // swizzled source slot
  int rb = 4 * (lane >> 4);

  if (blockIdx.x < 512) {
    // ---- KV projection: M=4096, N=2048, K=1024, nt=32 ----
    const unsigned short* Bw = wqkvb + (size_t)DIM * DIM;
    int flat = blockIdx.x;
    int xcd = flat & 7, i8 = flat >> 3;
    int tile = xcd * 64 + i8;
    int bx = tile & 15, by = tile >> 4;
    int bm = by * 128, bn = bx * 128;
    const int K = DIM, N = 2 * DIM, nt = 32;

    const unsigned short* ap[2];
    const unsigned short* bp[2];
#pragma unroll
    for (int c = 0; c < 2; ++c) {
      int row = (wave * 2 + c) * 16 + srow;
      ap[c] = xb + (size_t)(bm + row) * K + scol;
      bp[c] = Bw + (size_t)(bn + row) * K + scol;
    }
    f32x4 acc[4][4] = {};
#pragma unroll
    for (int pb = 0; pb < 2; ++pb) {
#pragma unroll
      for (int c = 0; c < 2; ++c) {
        int ch = wave * 2 + c;
        gload16(ap[c], (char*)As[pb] + ch * 1024 + lane * 16);
        gload16(bp[c], (char*)Bs[pb] + ch * 1024 + lane * 16);
        ap[c] += 32; bp[c] += 32;
      }
    }
    int cur = 0;
    for (int t = 0; t < nt; ++t) {
      if (t + 1 < nt) asm volatile("s_waitcnt vmcnt(4)" ::: "memory");
      else            asm volatile("s_waitcnt vmcnt(0)" ::: "memory");
      __builtin_amdgcn_s_barrier();
      asm volatile("" ::: "memory");
      __builtin_amdgcn_sched_barrier(0);
      short8 af[4], bf[4];
#pragma unroll
      for (int m = 0; m < 4; ++m) af[m] = *(const short8*)&As[cur][(wr + m*16 + lr)*32 + sx];
#pragma unroll
      for (int n = 0; n < 4; ++n) bf[n] = *(const short8*)&Bs[cur][(wc + n*16 + lr)*32 + sx];
      if (t + 2 < nt) {
        int nb = cur + 2; if (nb >= 3) nb -= 3;
#pragma unroll
        for (int c = 0; c < 2; ++c) {
          int ch = wave * 2 + c;
          gload16(ap[c], (char*)As[nb] + ch * 1024 + lane * 16);
          gload16(bp[c], (char*)Bs[nb] + ch * 1024 + lane * 16);
          ap[c] += 32; bp[c] += 32;
        }
      }
#pragma unroll
      for (int m = 0; m < 4; ++m)
#pragma unroll
        for (int n = 0; n < 4; ++n)
          acc[m][n] = __builtin_amdgcn_mfma_f32_16x16x32_bf16(af[m], bf[n], acc[m][n], 0, 0, 0);
      cur = (cur + 1 == 3) ? 0 : cur + 1;
    }
#pragma unroll
    for (int m = 0; m < 4; ++m) {
#pragma unroll
      for (int n = 0; n < 4; ++n) {
        int col = bn + wc + n*16 + lr;
        float bv = Wqkv_b[DIM + col];
#pragma unroll
        for (int i = 0; i < 4; ++i) {
          int row = bm + wr + m*16 + rb + i;
          kvb[(size_t)row * N + col] = f2bf(acc[m][n][i] + bv);
        }
      }
    }
  } else {
    // ---- Q split-K gather GEMM: M=MPAD, N=DIM, K-slice 128, nt=4 ----
    int bi = blockIdx.x - 512;     // 0..63
    int sk = bi >> 3;
    int bn = (bi & 7) * 128;
    int kb = sk * 128;
    const int K = DIM, N = DIM, nt = 4;

    const unsigned short* ap[2];
    const unsigned short* bp[2];
#pragma unroll
    for (int c = 0; c < 2; ++c) {
      int row = (wave * 2 + c) * 16 + srow;
      int bb = 0, rr = 0;
      if (row < NSEL) { bb = row / KK; rr = idxp[row]; }
      ap[c] = xb + ((size_t)(bb * SEQ + rr)) * K + kb + scol;
      bp[c] = wqkvb + (size_t)(bn + row) * K + kb + scol;
    }
    f32x4 acc[4][4] = {};
#pragma unroll
    for (int pb = 0; pb < 2; ++pb) {
#pragma unroll
      for (int c = 0; c < 2; ++c) {
        int ch = wave * 2 + c;
        gload16(ap[c], (char*)As[pb] + ch * 1024 + lane * 16);
        gload16(bp[c], (char*)Bs[pb] + ch * 1024 + lane * 16);
        ap[c] += 32; bp[c] += 32;
      }
    }
    int cur = 0;
    for (int t = 0; t < nt; ++t) {
      if (t + 1 < nt) asm volatile("s_waitcnt vmcnt(4)" ::: "memory");
      else            asm volatile("s_waitcnt vmcnt(0)" ::: "memory");
      __builtin_amdgcn_s_barrier();
      asm volatile("" ::: "memory");
      __builtin_amdgcn_sched_barrier(0);
      short8 af[4], bf[4];
#pragma unroll
      for (int m = 0; m < 4; ++m) af[m] = *(const short8*)&As[cur][(wr + m*16 + lr)*32 + sx];
#pragma unroll
      for (int n = 0; n < 4; ++n) bf[n] = *(const short8*)&Bs[cur][(wc + n*16 + lr)*32 + sx];
      if (t + 2 < nt) {
        int nb = cur + 2; if (nb >= 3) nb -= 3;
#pragma unroll
        for (int c = 0; c < 2; ++c) {
          int ch = wave * 2 + c;
          gload16(ap[c], (char*)As[nb] + ch * 1024 + lane * 16);
          gload16(bp[c], (char*)Bs[nb] + ch * 1024 + lane * 16);
          ap[c] += 32; bp[c] += 32;
        }
      }
#pragma unroll
      for (int m = 0; m < 4; ++m)
#pragma unroll
        for (int n = 0; n < 4; ++n)
          acc[m][n] = __builtin_amdgcn_mfma_f32_16x16x32_bf16(af[m], bf[n], acc[m][n], 0, 0, 0);
      cur = (cur + 1 == 3) ? 0 : cur + 1;
    }
    float* po = qpart + (size_t)sk * MPAD * N;
#pragma unroll
    for (int m = 0; m < 4; ++m) {
#pragma unroll
      for (int n = 0; n < 4; ++n) {
        int col = bn + wc + n*16 + lr;
#pragma unroll
        for (int i = 0; i < 4; ++i) {
          int row = wr + m*16 + rb + i;
          po[(size_t)row * N + col] = acc[m][n][i];
        }
      }
    }
  }
}

// Out-proj split-K with FUSED attention combine: block (bn, sk) computes its
// A-tile (ctx rows x cols kb..kb+127 = heads 2sk,2sk+1) from Opart/mpart/lpart
// directly into LDS (bf16, same rounding as the old ctxg path), then runs the
// 3-buffer B pipeline (vmcnt(2) counted).
__global__ __launch_bounds__(256) void gemm_splitk_kernel(
    const float* __restrict__ Opart,
    const float* __restrict__ mpart,
    const float* __restrict__ lpart,
    const unsigned short* __restrict__ Bw,   // outwb
    float* __restrict__ part)
{
  __shared__ unsigned short ASf[128][136];   // padded, linear
  __shared__ unsigned short Bs[3][128*32];
  int tid  = threadIdx.x;
  int lane = tid & 63, wave = tid >> 6;
  int wr = (wave >> 1) * 64, wc = (wave & 1) * 64;
  int bn = blockIdx.x * 128;
  int sk = blockIdx.z;
  int kb  = sk * 128;
  const int K = DIM, N = DIM, nt = 4;

  int lr = lane & 15, hk8 = (lane >> 4) * 8;
  int srow = lane >> 2;
  int scol = (((lane & 3) ^ ((lane >> 3) & 3)) << 3);
  int sx = (((lane >> 4) ^ ((lane >> 1) & 3)) << 3);

  // B staging pointers + prologue (tiles 0,1)
  const unsigned short* bp[2];
#pragma unroll
  for (int c = 0; c < 2; ++c) {
    int row = (wave * 2 + c) * 16 + srow;
    bp[c] = Bw + (size_t)(bn + row) * K + kb + scol;
  }
#pragma unroll
  for (int pb = 0; pb < 2; ++pb) {
#pragma unroll
    for (int c = 0; c < 2; ++c) {
      int ch = wave * 2 + c;
      gload16(bp[c], (char*)Bs[pb] + ch * 1024 + lane * 16);
      bp[c] += 32;
    }
  }

  // ---- fused combine: thread -> (row j, head-half) ----
  {
    int j = tid & 127, half = tid >> 7;
    int h = (kb >> 6) + half;            // 2*sk + half
    if (j < NSEL) {
      int b = j / KK, q = j - b * KK;
      size_t mb = (size_t)(b * NH + h) * NCH;
      float M = -3e38f;
#pragma unroll
      for (int c = 0; c < NCH; ++c) M = fmaxf(M, mpart[(mb + c) * KK + q]);
      float o[64];
#pragma unroll
      for (int d = 0; d < 64; ++d) o[d] = 0.f;
      float L = 0.f;
#pragma unroll
      for (int c = 0; c < NCH; ++c) {
        float f = __expf(mpart[(mb + c) * KK + q] - M);
        L += lpart[(mb + c) * KK + q] * f;
        const float* op = Opart + ((mb + c) * KK + q) * HD;
#pragma unroll
        for (int d4 = 0; d4 < 16; ++d4) {
          float4 v = *(const float4*)(op + d4 * 4);
          o[d4*4+0] = fmaf(v.x, f, o[d4*4+0]);
          o[d4*4+1] = fmaf(v.y, f, o[d4*4+1]);
          o[d4*4+2] = fmaf(v.z, f, o[d4*4+2]);
          o[d4*4+3] = fmaf(v.w, f, o[d4*4+3]);
        }
      }
      float inv = 1.f / L;
#pragma unroll
      for (int d = 0; d < 64; ++d)
        ASf[j][half * 64 + d] = f2bf(o[d] * inv);
    } else {
#pragma unroll
      for (int d = 0; d < 64; ++d) ASf[j][half * 64 + d] = 0;
    }
  }
  asm volatile("s_waitcnt lgkmcnt(0)" ::: "memory");

  f32x4 acc[4][4] = {};
  int cur = 0;
  for (int t = 0; t < nt; ++t) {
    if (t + 1 < nt) asm volatile("s_waitcnt vmcnt(2)" ::: "memory");
    else            asm volatile("s_waitcnt vmcnt(0)" ::: "memory");
    __builtin_amdgcn_s_barrier();
    asm volatile("" ::: "memory");
    __builtin_amdgcn_sched_barrier(0);
    short8 af[4], bf[4];
#pragma unroll
    for (int m = 0; m < 4; ++m) af[m] = *(const short8*)&ASf[wr + m*16 + lr][t*32 + hk8];
#pragma unroll
    for (int n = 0; n < 4; ++n) bf[n] = *(const short8*)&Bs[cur][(wc + n*16 + lr)*32 + sx];
    if (t + 2 < nt) {
      int nb = cur + 2; if (nb >= 3) nb -= 3;
#pragma unroll
      for (int c = 0; c < 2; ++c) {
        int ch = wave * 2 + c;
        gload16(bp[c], (char*)Bs[nb] + ch * 1024 + lane * 16);
        bp[c] += 32;
      }
    }
#pragma unroll
    for (int m = 0; m < 4; ++m)
#pragma unroll
      for (int n = 0; n < 4; ++n)
        acc[m][n] = __builtin_amdgcn_mfma_f32_16x16x32_bf16(af[m], bf[n], acc[m][n], 0, 0, 0);
    cur = (cur + 1 == 3) ? 0 : cur + 1;
  }

  int rb = 4 * (lane >> 4);
  float* po = part + (size_t)sk * MPAD * N;
#pragma unroll
  for (int m = 0; m < 4; ++m) {
#pragma unroll
    for (int n = 0; n < 4; ++n) {
      int col = bn + wc + n*16 + lr;
#pragma unroll
      for (int i = 0; i < 4; ++i) {
        int row = wr + m*16 + rb + i;
        po[(size_t)row * N + col] = acc[m][n][i];
      }
    }
  }
}

// MFMA flash-chunk attention. Grid (NH, BATCH, NCH), 256 threads (4 waves).
// Q staged directly from split-K partials (qcombine fused): sum 8 slices + bias.
__global__ __launch_bounds__(256) void attn_chunk_kernel(
    const float* __restrict__ qpart,     // [SPLITK][MPAD][DIM] f32
    const float* __restrict__ Wqkv_b,    // Q bias = [0..DIM)
    const unsigned short* __restrict__ kvb,
    const int* __restrict__ idx,
    float* __restrict__ Opart,
    float* __restrict__ mpart,
    float* __restrict__ lpart)
{
  int h = blockIdx.x, b = blockIdx.y, kc = blockIdx.z;
  int t = threadIdx.x, lane = t & 63, w = t >> 6;
  int lr = lane & 15, hk = lane >> 4;

  __shared__ unsigned short Qs[QP][72];
  __shared__ union { unsigned short Ks[CHUNK][72]; unsigned short ps[QP][136]; } U;
  __shared__ unsigned short Vt[HD][134];
  __shared__ int   rsi[QP];
  __shared__ float wred[4][QP];
  __shared__ float wsum[4][QP];

  if (t < QP) rsi[t] = (t < KK) ? idx[b*KK + t] : -1;
  for (int i = t; i < QP*8; i += 256) {
    int q = i >> 3, c8 = (i & 7) * 8;
    if (q < KK) {
      int j = b*KK + q;
      float4 b0 = *(const float4*)(Wqkv_b + h*HD + c8);
      float4 b1 = *(const float4*)(Wqkv_b + h*HD + c8 + 4);
      float v0 = b0.x, v1 = b0.y, v2 = b0.z, v3 = b0.w;
      float v4 = b1.x, v5 = b1.y, v6 = b1.z, v7 = b1.w;
#pragma unroll
      for (int sk = 0; sk < SPLITK; ++sk) {
        const float* p = qpart + ((size_t)sk * MPAD + j) * DIM + h*HD + c8;
        float4 a0 = *(const float4*)p;
        float4 a1 = *(const float4*)(p + 4);
        v0 += a0.x; v1 += a0.y; v2 += a0.z; v3 += a0.w;
        v4 += a1.x; v5 += a1.y; v6 += a1.z; v7 += a1.w;
      }
      Qs[q][c8+0] = f2bf(v0); Qs[q][c8+1] = f2bf(v1);
      Qs[q][c8+2] = f2bf(v2); Qs[q][c8+3] = f2bf(v3);
      Qs[q][c8+4] = f2bf(v4); Qs[q][c8+5] = f2bf(v5);
      Qs[q][c8+6] = f2bf(v6); Qs[q][c8+7] = f2bf(v7);
    } else {
      uint4 zz; zz.x = 0; zz.y = 0; zz.z = 0; zz.w = 0;
      *(uint4*)&Qs[q][c8] = zz;
    }
  }
  for (int i = t; i < CHUNK*8; i += 256) {
    int r = i >> 3, c8 = (i & 7) * 8;
    *(uint4*)&U.Ks[r][c8] =
      *(const uint4*)(kvb + ((size_t)(b*SEQ + kc*CHUNK + r))*2048 + h*HD + c8);
  }
  for (int i = t; i < CHUNK*8; i += 256) {
    int r = i >> 3, d8 = (i & 7) * 8;
    uint4 v = *(const uint4*)(kvb + ((size_t)(b*SEQ + kc*CHUNK + r))*2048 + DIM + h*HD + d8);
    const unsigned short* pv = (const unsigned short*)&v;
#pragma unroll
    for (int j = 0; j < 8; ++j) Vt[d8 + j][r] = pv[j];
  }
  __syncthreads();

  short8 af[3][2], bfr[2][2];
#pragma unroll
  for (int m = 0; m < 3; ++m)
#pragma unroll
    for (int kk = 0; kk < 2; ++kk)
      af[m][kk] = *(const short8*)&Qs[m*16 + lr][kk*32 + hk*8];
#pragma unroll
  for (int j = 0; j < 2; ++j)
#pragma unroll
    for (int kk = 0; kk < 2; ++kk)
      bfr[j][kk] = *(const short8*)&U.Ks[(2*w + j)*16 + lr][kk*32 + hk*8];
  f32x4 acc[3][2] = {};
#pragma unroll
  for (int kk = 0; kk < 2; ++kk)
#pragma unroll
    for (int m = 0; m < 3; ++m)
#pragma unroll
      for (int j = 0; j < 2; ++j)
        acc[m][j] = __builtin_amdgcn_mfma_f32_16x16x32_bf16(af[m][kk], bfr[j][kk], acc[m][j], 0, 0, 0);

  float s[3][2][4];
  float rmax[3][4];
#pragma unroll
  for (int m = 0; m < 3; ++m)
#pragma unroll
    for (int reg = 0; reg < 4; ++reg) {
      int row = m*16 + hk*4 + reg;
      int rq = rsi[row];
      float mx = -3e38f;
#pragma unroll
      for (int j = 0; j < 2; ++j) {
        int gkey = kc*CHUNK + (2*w + j)*16 + lr;
        float v = acc[m][j][reg] * 0.125f;
        if (gkey > rq) v = -3e38f;
        s[m][j][reg] = v;
        mx = fmaxf(mx, v);
      }
#pragma unroll
      for (int o = 1; o < 16; o <<= 1) mx = fmaxf(mx, __shfl_xor(mx, o));
      rmax[m][reg] = mx;
    }
  if (lr == 0) {
#pragma unroll
    for (int m = 0; m < 3; ++m)
#pragma unroll
      for (int reg = 0; reg < 4; ++reg)
        wred[w][m*16 + hk*4 + reg] = rmax[m][reg];
  }
  __syncthreads();

  float rsum[3][4];
#pragma unroll
  for (int m = 0; m < 3; ++m)
#pragma unroll
    for (int reg = 0; reg < 4; ++reg) {
      int row = m*16 + hk*4 + reg;
      float gm = fmaxf(fmaxf(wred[0][row], wred[1][row]), fmaxf(wred[2][row], wred[3][row]));
      gm = fmaxf(gm, -1e37f);
      float sum = 0.f;
#pragma unroll
      for (int j = 0; j < 2; ++j) {
        float p = __expf(s[m][j][reg] - gm);
        sum += p;
        U.ps[row][(2*w + j)*16 + lr] = f2bf(p);
      }
#pragma unroll
      for (int o = 1; o < 16; o <<= 1) sum += __shfl_xor(sum, o);
      rsum[m][reg] = sum;
      rmax[m][reg] = gm;
    }
  if (lr == 0) {
#pragma unroll
    for (int m = 0; m < 3; ++m)
#pragma unroll
      for (int reg = 0; reg < 4; ++reg)
        wsum[w][m*16 + hk*4 + reg] = rsum[m][reg];
  }
  __syncthreads();

  if (w == 0 && lr == 0) {
    size_t base = ((size_t)(b*NH + h)*NCH + kc)*KK;
#pragma unroll
    for (int m = 0; m < 3; ++m)
#pragma unroll
      for (int reg = 0; reg < 4; ++reg) {
        int row = m*16 + hk*4 + reg;
        if (row < KK) {
          float L = wsum[0][row] + wsum[1][row] + wsum[2][row] + wsum[3][row];
          mpart[base + row] = rmax[m][reg];
          lpart[base + row] = L;
        }
      }
  }

  f32x4 acc2[3] = {};
#pragma unroll
  for (int kt = 0; kt < 4; ++kt) {
    short8 bv = *(const short8*)&Vt[w*16 + lr][kt*32 + hk*8];
#pragma unroll
    for (int m = 0; m < 3; ++m) {
      short8 av = *(const short8*)&U.ps[m*16 + lr][kt*32 + hk*8];
      acc2[m] = __builtin_amdgcn_mfma_f32_16x16x32_bf16(av, bv, acc2[m], 0, 0, 0);
    }
  }
  size_t obase = (((size_t)(b*NH + h)*NCH + kc)*KK)*HD;
#pragma unroll
  for (int m = 0; m < 3; ++m)
#pragma unroll
    for (int reg = 0; reg < 4; ++reg) {
      int q = m*16 + hk*4 + reg;
      if (q < KK) Opart[obase + (size_t)q*HD + w*16 + lr] = acc2[m][reg];
    }
}

// out[selrow] = x[selrow] + (sum_sk apart[sk][j] + out_b) * sel[selrow].
__global__ void rowfix_kernel(const float* __restrict__ x,
                              const float* __restrict__ apart,
                              const float* __restrict__ out_b,
                              const float* __restrict__ sel,
                              const int* __restrict__ idx,
                              float* __restrict__ out)
{
  int j = blockIdx.x;           // 0..NSEL-1
  int b = j / KK;
  int r = idx[j];
  int col = threadIdx.x * 4;
  size_t off = ((size_t)(b * SEQ + r)) * DIM + col;
  float s = sel[b * SEQ + r];
  float4 a = *(const float4*)(out_b + col);
#pragma unroll
  for (int sk = 0; sk < SPLITK; ++sk) {
    float4 p = *(const float4*)(apart + ((size_t)sk * MPAD + j) * DIM + col);
    a.x += p.x; a.y += p.y; a.z += p.z; a.w += p.w;
  }
  float4 v = *(const float4*)(x + off);
  v.x += a.x * s; v.y += a.y * s; v.z += a.z * s; v.w += a.w * s;
  *(float4*)(out + off) = v;
}

extern "C" void kernel_launch(void* const* d_in, const int* in_sizes, int n_in,
                              void* d_out, int out_size, void* d_ws, size_t ws_size,
                              hipStream_t stream)
{
  (void)in_sizes; (void)n_in; (void)out_size; (void)ws_size;
  const float* x      = (const float*)d_in[0];
  const float* Wqkv_w = (const float*)d_in[1];
  const float* Wqkv_b = (const float*)d_in[2];
  const float* sel_w  = (const float*)d_in[3];
  const float* sel_b  = (const float*)d_in[4];
  const float* out_w  = (const float*)d_in[5];
  const float* out_b  = (const float*)d_in[6];
  float* out = (float*)d_out;
  char* ws = (char*)d_ws;

  unsigned short* xb    = (unsigned short*)(ws);                        // 8 MB
  unsigned short* wqkvb = (unsigned short*)(ws + (8u  << 20));          // 6 MB
  unsigned short* outwb = (unsigned short*)(ws + (14u << 20));          // 2 MB
  unsigned short* kvb   = (unsigned short*)(ws + (16u << 20));          // 16 MB
  float* z      = (float*)(ws + (32u << 20));                           // 16 KB
  float* sel    = (float*)(ws + (32u << 20) + (16u << 10));             // 16 KB
  int*   idx    = (int*)  (ws + (32u << 20) + (32u << 10));             // ~1 KB
  float* Opart = (float*)(ws + (35u << 20));                            // 6.0 MB
  float* mpart = (float*)(ws + (42u << 20));                            // 94 KB
  float* lpart = (float*)(ws + (42u << 20) + (256u << 10));             // 94 KB
  float* qpart = (float*)(ws + (44u << 20));                            // 4 MB
  float* apart = (float*)(ws + (48u << 20));                            // 4 MB

  prep_kernel<<<3072, 256, 0, stream>>>(Wqkv_w, out_w, wqkvb, outwb,
                                        x, xb, sel_w, sel_b, z, out);
  topk_kernel<<<BATCH, 256, 0, stream>>>(z, sel, idx);

  gemms_kernel<<<576, 256, 0, stream>>>(xb, wqkvb, Wqkv_b, kvb, qpart, idx);

  dim3 gac(NH, BATCH, NCH);
  attn_chunk_kernel<<<gac, 256, 0, stream>>>(qpart, Wqkv_b, kvb, idx, Opart, mpart, lpart);

  dim3 gsk(DIM/128, 1, SPLITK);
  gemm_splitk_kernel<<<gsk, 256, 0, stream>>>(Opart, mpart, lpart, outwb, apart);

  rowfix_kernel<<<NSEL, 256, 0, stream>>>(x, apart, out_b, sel, idx, out);
}

// Round 21
// 69.687 us; speedup vs baseline: 1.4342x; 1.4342x over previous
//
#include <hip/hip_runtime.h>
#include <stdint.h>

#define BATCH 2
#define SEQ   2048
#define DIM   1024
#define NH    16
#define HD    64
#define KK    46
#define NSEL  (BATCH*KK)   // 92
#define MPAD  128
#define CHUNK 128
#define NCH   (SEQ/CHUNK)  // 16
#define QP    48           // padded query rows (3 MFMA m-tiles)
#define SPLITK 8

typedef __attribute__((ext_vector_type(8))) short short8;
typedef __attribute__((ext_vector_type(4))) float f32x4;

__device__ inline unsigned short f2bf(float f) {
  union { float f; uint32_t u; } v; v.f = f;
  uint32_t u = v.u;
  uint32_t r = u + 0x7fff + ((u >> 16) & 1);
  return (unsigned short)(r >> 16);
}
__device__ inline float bf2f(unsigned short h) {
  union { uint32_t u; float f; } v; v.u = ((uint32_t)h) << 16;
  return v.f;
}
__device__ inline uint32_t f2ord(float f) {
  union { float f; uint32_t u; } v; v.f = f;
  return (v.u & 0x80000000u) ? ~v.u : (v.u | 0x80000000u);
}

// async global->LDS, 16B per lane; LDS dest = wave-uniform base + lane*16
__device__ inline void gload16(const void* g, void* l) {
  __builtin_amdgcn_global_load_lds(
      (const __attribute__((address_space(1))) void*)g,
      (__attribute__((address_space(3))) void*)l, 16, 0, 0);
}

// Merged prep: blocks 0..2047 convert weights; blocks 2048..3071: x row ->
// bf16 xb + selz dot + out base copy.
__global__ __launch_bounds__(256) void prep_kernel(
    const float* __restrict__ wqkv, const float* __restrict__ outw,
    unsigned short* __restrict__ wqkvb, unsigned short* __restrict__ outwb,
    const float* __restrict__ x, unsigned short* __restrict__ xb,
    const float* __restrict__ sel_w, const float* __restrict__ sel_b,
    float* __restrict__ z, float* __restrict__ out)
{
  if (blockIdx.x < 2048) {
    int i = (blockIdx.x * 256 + threadIdx.x) * 8;
    const int NW = 3 * DIM * DIM;
    const float* src; unsigned short* dst; int j;
    if (i < NW) { src = wqkv; dst = wqkvb; j = i; }
    else        { src = outw; dst = outwb; j = i - NW; }
    float4 a = *(const float4*)(src + j);
    float4 b = *(const float4*)(src + j + 4);
    ushort4 o0, o1;
    o0.x = f2bf(a.x); o0.y = f2bf(a.y); o0.z = f2bf(a.z); o0.w = f2bf(a.w);
    o1.x = f2bf(b.x); o1.y = f2bf(b.y); o1.z = f2bf(b.z); o1.w = f2bf(b.w);
    *(ushort4*)(dst + j)     = o0;
    *(ushort4*)(dst + j + 4) = o1;
  } else {
    int wave = threadIdx.x >> 6, lane = threadIdx.x & 63;
    int row = (blockIdx.x - 2048) * 4 + wave;
    const float* xr = x + (size_t)row * DIM;
    unsigned short* xo = xb + (size_t)row * DIM;
    float* oo = out + (size_t)row * DIM;
    float s = 0.f;
#pragma unroll
    for (int it = 0; it < 4; ++it) {
      int c = it * 256 + lane * 4;
      float4 xv = *(const float4*)(xr + c);
      float4 wv = *(const float4*)(sel_w + c);
      s += xv.x*wv.x + xv.y*wv.y + xv.z*wv.z + xv.w*wv.w;
      ushort4 o;
      o.x = f2bf(xv.x); o.y = f2bf(xv.y); o.z = f2bf(xv.z); o.w = f2bf(xv.w);
      *(ushort4*)(xo + c) = o;
      *(float4*)(oo + c) = xv;
    }
#pragma unroll
    for (int o = 32; o > 0; o >>= 1) s += __shfl_xor(s, o);
    if (lane == 0) z[row] = s + sel_b[0];
  }
}

// Radix-select top-KK + softmax(sel). One block per batch.
__global__ __launch_bounds__(256) void topk_kernel(const float* __restrict__ z,
                                                   float* __restrict__ sel,
                                                   int* __restrict__ idxout)
{
  int b = blockIdx.x, t = threadIdx.x;
  int lane = t & 63, wid = t >> 6;
  __shared__ int   hist[256];
  __shared__ float fred[4];
  __shared__ int   ired[4];
  __shared__ int   s_B, s_need;
  __shared__ float s_mx, s_sum;

  int s0 = t * 8;
  float zz[8];
  uint32_t uu[8];
  {
    float4 a = *(const float4*)(z + b*SEQ + s0);
    float4 c = *(const float4*)(z + b*SEQ + s0 + 4);
    zz[0]=a.x; zz[1]=a.y; zz[2]=a.z; zz[3]=a.w;
    zz[4]=c.x; zz[5]=c.y; zz[6]=c.z; zz[7]=c.w;
  }
#pragma unroll
  for (int i = 0; i < 8; ++i) uu[i] = f2ord(zz[i]);

  float lm = zz[0];
#pragma unroll
  for (int i = 1; i < 8; ++i) lm = fmaxf(lm, zz[i]);
#pragma unroll
  for (int o = 32; o > 0; o >>= 1) lm = fmaxf(lm, __shfl_xor(lm, o));
  if (lane == 0) fred[wid] = lm;
  __syncthreads();
  if (t == 0) s_mx = fmaxf(fmaxf(fred[0], fred[1]), fmaxf(fred[2], fred[3]));
  __syncthreads();
  float mx = s_mx;

  float pp[8];
  float ls = 0.f;
#pragma unroll
  for (int i = 0; i < 8; ++i) { pp[i] = __expf(zz[i] - mx); ls += pp[i]; }
#pragma unroll
  for (int o = 32; o > 0; o >>= 1) ls += __shfl_xor(ls, o);
  if (lane == 0) fred[wid] = ls;
  __syncthreads();
  if (t == 0) s_sum = fred[0] + fred[1] + fred[2] + fred[3];
  __syncthreads();
  float sscale = 4.0f / s_sum;   // sqrt(DIM)/8 = 4
#pragma unroll
  for (int i = 0; i < 8; ++i) sel[b*SEQ + s0 + i] = pp[i] * sscale;

  uint32_t pref = 0;
  int need = KK;
#pragma unroll
  for (int pass = 0; pass < 4; ++pass) {
    int shift = 24 - pass * 8;
    uint32_t maskhi = pass ? (0xFFFFFFFFu << (shift + 8)) : 0u;
    hist[t] = 0;
    __syncthreads();
#pragma unroll
    for (int i = 0; i < 8; ++i) {
      if ((uu[i] & maskhi) == pref)
        atomicAdd(&hist[(uu[i] >> shift) & 255], 1);
    }
    __syncthreads();
    if (t < 64) {
      int c0 = hist[t*4], c1 = hist[t*4+1], c2 = hist[t*4+2], c3 = hist[t*4+3];
      int sl = c0 + c1 + c2 + c3;
      int suf = sl;
#pragma unroll
      for (int off = 1; off < 64; off <<= 1) {
        int o = __shfl_down(suf, off);
        if (lane + off < 64) suf += o;
      }
      int above = suf - sl;
      if (above < need && above + sl >= need) {
        int cum = above;
        int cs[4] = {c0, c1, c2, c3};
#pragma unroll
        for (int k = 3; k >= 0; --k) {
          if (cum < need && cum + cs[k] >= need) {
            s_B = t*4 + k;
            s_need = need - cum;
            break;
          }
          cum += cs[k];
        }
      }
    }
    __syncthreads();
    pref |= ((uint32_t)s_B) << shift;
    need = s_need;
    __syncthreads();
  }
  uint32_t T = pref;

  int cgt = 0, ceq = 0;
#pragma unroll
  for (int i = 0; i < 8; ++i) { cgt += (uu[i] > T); ceq += (uu[i] == T); }
  int pack = (cgt << 12) | ceq;
  int inc = pack;
#pragma unroll
  for (int off = 1; off < 64; off <<= 1) {
    int o = __shfl_up(inc, off);
    if (lane >= off) inc += o;
  }
  if (lane == 63) ired[wid] = inc;
  __syncthreads();
  int wbase = 0;
  if (wid == 1) wbase = ired[0];
  else if (wid == 2) wbase = ired[0] + ired[1];
  else if (wid == 3) wbase = ired[0] + ired[1] + ired[2];
  int ex = wbase + inc - pack;
  int g = ex >> 12, e = ex & 0xFFF;
#pragma unroll
  for (int i = 0; i < 8; ++i) {
    int s = s0 + i;
    bool isgt = uu[i] > T;
    bool iseq = uu[i] == T;
    int rank = -1;
    if (isgt) rank = g + (e < need ? e : need);
    else if (iseq && e < need) rank = g + e;
    if (rank >= 0) idxout[b*KK + rank] = s;
    g += isgt; e += iseq;
  }
}

// Merged GEMM launch: blocks 0..511 = KV projection; 512..575 = Q split-K gather.
// 4 waves, 128x128 tile, XOR-swizzled LDS. 3-buffer depth-2 pipeline:
// raw s_barrier + counted vmcnt(4); stage(t+2) issued post-barrier (WAR-safe).
__global__ __launch_bounds__(256) void gemms_kernel(
    const unsigned short* __restrict__ xb,
    const unsigned short* __restrict__ wqkvb,
    const float* __restrict__ Wqkv_b,
    unsigned short* __restrict__ kvb,
    float* __restrict__ qpart,
    const int* __restrict__ idxp)
{
  __shared__ unsigned short As[3][128*32];
  __shared__ unsigned short Bs[3][128*32];
  int tid  = threadIdx.x;
  int lane = tid & 63, wave = tid >> 6;
  int wr = (wave >> 1) * 64, wc = (wave & 1) * 64;
  int lr = lane & 15;
  int sx = (((lane >> 4) ^ ((lane >> 1) & 3)) << 3);   // swizzled read slot
  int srow = lane >> 2;
  int scol = (((lane & 3) ^ ((lane >> 3) & 3)) << 3);  // swizzled source slot
  int rb = 4 * (lane >> 4);

  if (blockIdx.x < 512) {
    // ---- KV projection: M=4096, N=2048, K=1024, nt=32 ----
    const unsigned short* Bw = wqkvb + (size_t)DIM * DIM;
    int flat = blockIdx.x;
    int xcd = flat & 7, i8 = flat >> 3;
    int tile = xcd * 64 + i8;
    int bx = tile & 15, by = tile >> 4;
    int bm = by * 128, bn = bx * 128;
    const int K = DIM, N = 2 * DIM, nt = 32;

    const unsigned short* ap[2];
    const unsigned short* bp[2];
#pragma unroll
    for (int c = 0; c < 2; ++c) {
      int row = (wave * 2 + c) * 16 + srow;
      ap[c] = xb + (size_t)(bm + row) * K + scol;
      bp[c] = Bw + (size_t)(bn + row) * K + scol;
    }
    f32x4 acc[4][4] = {};
#pragma unroll
    for (int pb = 0; pb < 2; ++pb) {
#pragma unroll
      for (int c = 0; c < 2; ++c) {
        int ch = wave * 2 + c;
        gload16(ap[c], (char*)As[pb] + ch * 1024 + lane * 16);
        gload16(bp[c], (char*)Bs[pb] + ch * 1024 + lane * 16);
        ap[c] += 32; bp[c] += 32;
      }
    }
    int cur = 0;
    for (int t = 0; t < nt; ++t) {
      if (t + 1 < nt) asm volatile("s_waitcnt vmcnt(4)" ::: "memory");
      else            asm volatile("s_waitcnt vmcnt(0)" ::: "memory");
      __builtin_amdgcn_s_barrier();
      asm volatile("" ::: "memory");
      __builtin_amdgcn_sched_barrier(0);
      short8 af[4], bf[4];
#pragma unroll
      for (int m = 0; m < 4; ++m) af[m] = *(const short8*)&As[cur][(wr + m*16 + lr)*32 + sx];
#pragma unroll
      for (int n = 0; n < 4; ++n) bf[n] = *(const short8*)&Bs[cur][(wc + n*16 + lr)*32 + sx];
      if (t + 2 < nt) {
        int nb = cur + 2; if (nb >= 3) nb -= 3;
#pragma unroll
        for (int c = 0; c < 2; ++c) {
          int ch = wave * 2 + c;
          gload16(ap[c], (char*)As[nb] + ch * 1024 + lane * 16);
          gload16(bp[c], (char*)Bs[nb] + ch * 1024 + lane * 16);
          ap[c] += 32; bp[c] += 32;
        }
      }
#pragma unroll
      for (int m = 0; m < 4; ++m)
#pragma unroll
        for (int n = 0; n < 4; ++n)
          acc[m][n] = __builtin_amdgcn_mfma_f32_16x16x32_bf16(af[m], bf[n], acc[m][n], 0, 0, 0);
      cur = (cur + 1 == 3) ? 0 : cur + 1;
    }
#pragma unroll
    for (int m = 0; m < 4; ++m) {
#pragma unroll
      for (int n = 0; n < 4; ++n) {
        int col = bn + wc + n*16 + lr;
        float bv = Wqkv_b[DIM + col];
#pragma unroll
        for (int i = 0; i < 4; ++i) {
          int row = bm + wr + m*16 + rb + i;
          kvb[(size_t)row * N + col] = f2bf(acc[m][n][i] + bv);
        }
      }
    }
  } else {
    // ---- Q split-K gather GEMM: M=MPAD, N=DIM, K-slice 128, nt=4 ----
    int bi = blockIdx.x - 512;     // 0..63
    int sk = bi >> 3;
    int bn = (bi & 7) * 128;
    int kb = sk * 128;
    const int K = DIM, N = DIM, nt = 4;

    const unsigned short* ap[2];
    const unsigned short* bp[2];
#pragma unroll
    for (int c = 0; c < 2; ++c) {
      int row = (wave * 2 + c) * 16 + srow;
      int bb = 0, rr = 0;
      if (row < NSEL) { bb = row / KK; rr = idxp[row]; }
      ap[c] = xb + ((size_t)(bb * SEQ + rr)) * K + kb + scol;
      bp[c] = wqkvb + (size_t)(bn + row) * K + kb + scol;
    }
    f32x4 acc[4][4] = {};
#pragma unroll
    for (int pb = 0; pb < 2; ++pb) {
#pragma unroll
      for (int c = 0; c < 2; ++c) {
        int ch = wave * 2 + c;
        gload16(ap[c], (char*)As[pb] + ch * 1024 + lane * 16);
        gload16(bp[c], (char*)Bs[pb] + ch * 1024 + lane * 16);
        ap[c] += 32; bp[c] += 32;
      }
    }
    int cur = 0;
    for (int t = 0; t < nt; ++t) {
      if (t + 1 < nt) asm volatile("s_waitcnt vmcnt(4)" ::: "memory");
      else            asm volatile("s_waitcnt vmcnt(0)" ::: "memory");
      __builtin_amdgcn_s_barrier();
      asm volatile("" ::: "memory");
      __builtin_amdgcn_sched_barrier(0);
      short8 af[4], bf[4];
#pragma unroll
      for (int m = 0; m < 4; ++m) af[m] = *(const short8*)&As[cur][(wr + m*16 + lr)*32 + sx];
#pragma unroll
      for (int n = 0; n < 4; ++n) bf[n] = *(const short8*)&Bs[cur][(wc + n*16 + lr)*32 + sx];
      if (t + 2 < nt) {
        int nb = cur + 2; if (nb >= 3) nb -= 3;
#pragma unroll
        for (int c = 0; c < 2; ++c) {
          int ch = wave * 2 + c;
          gload16(ap[c], (char*)As[nb] + ch * 1024 + lane * 16);
          gload16(bp[c], (char*)Bs[nb] + ch * 1024 + lane * 16);
          ap[c] += 32; bp[c] += 32;
        }
      }
#pragma unroll
      for (int m = 0; m < 4; ++m)
#pragma unroll
        for (int n = 0; n < 4; ++n)
          acc[m][n] = __builtin_amdgcn_mfma_f32_16x16x32_bf16(af[m], bf[n], acc[m][n], 0, 0, 0);
      cur = (cur + 1 == 3) ? 0 : cur + 1;
    }
    float* po = qpart + (size_t)sk * MPAD * N;
#pragma unroll
    for (int m = 0; m < 4; ++m) {
#pragma unroll
      for (int n = 0; n < 4; ++n) {
        int col = bn + wc + n*16 + lr;
#pragma unroll
        for (int i = 0; i < 4; ++i) {
          int row = wr + m*16 + rb + i;
          po[(size_t)row * N + col] = acc[m][n][i];
        }
      }
    }
  }
}

// Split-K small GEMM for out-proj: 3-buffer depth-2 pipeline. nt=4.
__global__ __launch_bounds__(256) void gemm_splitk_kernel(
    const unsigned short* __restrict__ A,
    const unsigned short* __restrict__ Bw,
    float* __restrict__ part, int N, int K)
{
  __shared__ unsigned short As[3][128*32];
  __shared__ unsigned short Bs[3][128*32];
  int tid  = threadIdx.x;
  int lane = tid & 63, wave = tid >> 6;
  int wr = (wave >> 1) * 64, wc = (wave & 1) * 64;
  int bn = blockIdx.x * 128;
  int sk = blockIdx.z;
  int ksl = K / SPLITK;
  int kb  = sk * ksl;

  int lr = lane & 15;
  int sx = (((lane >> 4) ^ ((lane >> 1) & 3)) << 3);
  int srow = lane >> 2;
  int scol = (((lane & 3) ^ ((lane >> 3) & 3)) << 3);

  const unsigned short* ap[2];
  const unsigned short* bp[2];
#pragma unroll
  for (int c = 0; c < 2; ++c) {
    int row = (wave * 2 + c) * 16 + srow;
    ap[c] = A  + (size_t)row * K + kb + scol;
    bp[c] = Bw + (size_t)(bn + row) * K + kb + scol;
  }

  f32x4 acc[4][4] = {};
  const int nt = 4;
#pragma unroll
  for (int pb = 0; pb < 2; ++pb) {
#pragma unroll
    for (int c = 0; c < 2; ++c) {
      int ch = wave * 2 + c;
      gload16(ap[c], (char*)As[pb] + ch * 1024 + lane * 16);
      gload16(bp[c], (char*)Bs[pb] + ch * 1024 + lane * 16);
      ap[c] += 32; bp[c] += 32;
    }
  }
  int cur = 0;
  for (int t = 0; t < nt; ++t) {
    if (t + 1 < nt) asm volatile("s_waitcnt vmcnt(4)" ::: "memory");
    else            asm volatile("s_waitcnt vmcnt(0)" ::: "memory");
    __builtin_amdgcn_s_barrier();
    asm volatile("" ::: "memory");
    __builtin_amdgcn_sched_barrier(0);
    short8 af[4], bf[4];
#pragma unroll
    for (int m = 0; m < 4; ++m) af[m] = *(const short8*)&As[cur][(wr + m*16 + lr)*32 + sx];
#pragma unroll
    for (int n = 0; n < 4; ++n) bf[n] = *(const short8*)&Bs[cur][(wc + n*16 + lr)*32 + sx];
    if (t + 2 < nt) {
      int nb = cur + 2; if (nb >= 3) nb -= 3;
#pragma unroll
      for (int c = 0; c < 2; ++c) {
        int ch = wave * 2 + c;
        gload16(ap[c], (char*)As[nb] + ch * 1024 + lane * 16);
        gload16(bp[c], (char*)Bs[nb] + ch * 1024 + lane * 16);
        ap[c] += 32; bp[c] += 32;
      }
    }
#pragma unroll
    for (int m = 0; m < 4; ++m)
#pragma unroll
      for (int n = 0; n < 4; ++n)
        acc[m][n] = __builtin_amdgcn_mfma_f32_16x16x32_bf16(af[m], bf[n], acc[m][n], 0, 0, 0);
    cur = (cur + 1 == 3) ? 0 : cur + 1;
  }

  int rb = 4 * (lane >> 4);
  float* po = part + (size_t)sk * MPAD * N;
#pragma unroll
  for (int m = 0; m < 4; ++m) {
#pragma unroll
    for (int n = 0; n < 4; ++n) {
      int col = bn + wc + n*16 + lr;
#pragma unroll
      for (int i = 0; i < 4; ++i) {
        int row = wr + m*16 + rb + i;
        po[(size_t)row * N + col] = acc[m][n][i];
      }
    }
  }
}

// MFMA flash-chunk attention. Grid (NH, BATCH, NCH), 256 threads (4 waves).
// Q staged directly from split-K partials (qcombine fused): sum 8 slices + bias.
__global__ __launch_bounds__(256) void attn_chunk_kernel(
    const float* __restrict__ qpart,     // [SPLITK][MPAD][DIM] f32
    const float* __restrict__ Wqkv_b,    // Q bias = [0..DIM)
    const unsigned short* __restrict__ kvb,
    const int* __restrict__ idx,
    float* __restrict__ Opart,
    float* __restrict__ mpart,
    float* __restrict__ lpart)
{
  int h = blockIdx.x, b = blockIdx.y, kc = blockIdx.z;
  int t = threadIdx.x, lane = t & 63, w = t >> 6;
  int lr = lane & 15, hk = lane >> 4;

  __shared__ unsigned short Qs[QP][72];
  __shared__ union { unsigned short Ks[CHUNK][72]; unsigned short ps[QP][136]; } U;
  __shared__ unsigned short Vt[HD][134];
  __shared__ int   rsi[QP];
  __shared__ float wred[4][QP];
  __shared__ float wsum[4][QP];

  if (t < QP) rsi[t] = (t < KK) ? idx[b*KK + t] : -1;
  for (int i = t; i < QP*8; i += 256) {
    int q = i >> 3, c8 = (i & 7) * 8;
    if (q < KK) {
      int j = b*KK + q;
      float4 b0 = *(const float4*)(Wqkv_b + h*HD + c8);
      float4 b1 = *(const float4*)(Wqkv_b + h*HD + c8 + 4);
      float v0 = b0.x, v1 = b0.y, v2 = b0.z, v3 = b0.w;
      float v4 = b1.x, v5 = b1.y, v6 = b1.z, v7 = b1.w;
#pragma unroll
      for (int sk = 0; sk < SPLITK; ++sk) {
        const float* p = qpart + ((size_t)sk * MPAD + j) * DIM + h*HD + c8;
        float4 a0 = *(const float4*)p;
        float4 a1 = *(const float4*)(p + 4);
        v0 += a0.x; v1 += a0.y; v2 += a0.z; v3 += a0.w;
        v4 += a1.x; v5 += a1.y; v6 += a1.z; v7 += a1.w;
      }
      Qs[q][c8+0] = f2bf(v0); Qs[q][c8+1] = f2bf(v1);
      Qs[q][c8+2] = f2bf(v2); Qs[q][c8+3] = f2bf(v3);
      Qs[q][c8+4] = f2bf(v4); Qs[q][c8+5] = f2bf(v5);
      Qs[q][c8+6] = f2bf(v6); Qs[q][c8+7] = f2bf(v7);
    } else {
      uint4 zz; zz.x = 0; zz.y = 0; zz.z = 0; zz.w = 0;
      *(uint4*)&Qs[q][c8] = zz;
    }
  }
  for (int i = t; i < CHUNK*8; i += 256) {
    int r = i >> 3, c8 = (i & 7) * 8;
    *(uint4*)&U.Ks[r][c8] =
      *(const uint4*)(kvb + ((size_t)(b*SEQ + kc*CHUNK + r))*2048 + h*HD + c8);
  }
  for (int i = t; i < CHUNK*8; i += 256) {
    int r = i >> 3, d8 = (i & 7) * 8;
    uint4 v = *(const uint4*)(kvb + ((size_t)(b*SEQ + kc*CHUNK + r))*2048 + DIM + h*HD + d8);
    const unsigned short* pv = (const unsigned short*)&v;
#pragma unroll
    for (int j = 0; j < 8; ++j) Vt[d8 + j][r] = pv[j];
  }
  __syncthreads();

  short8 af[3][2], bfr[2][2];
#pragma unroll
  for (int m = 0; m < 3; ++m)
#pragma unroll
    for (int kk = 0; kk < 2; ++kk)
      af[m][kk] = *(const short8*)&Qs[m*16 + lr][kk*32 + hk*8];
#pragma unroll
  for (int j = 0; j < 2; ++j)
#pragma unroll
    for (int kk = 0; kk < 2; ++kk)
      bfr[j][kk] = *(const short8*)&U.Ks[(2*w + j)*16 + lr][kk*32 + hk*8];
  f32x4 acc[3][2] = {};
#pragma unroll
  for (int kk = 0; kk < 2; ++kk)
#pragma unroll
    for (int m = 0; m < 3; ++m)
#pragma unroll
      for (int j = 0; j < 2; ++j)
        acc[m][j] = __builtin_amdgcn_mfma_f32_16x16x32_bf16(af[m][kk], bfr[j][kk], acc[m][j], 0, 0, 0);

  float s[3][2][4];
  float rmax[3][4];
#pragma unroll
  for (int m = 0; m < 3; ++m)
#pragma unroll
    for (int reg = 0; reg < 4; ++reg) {
      int row = m*16 + hk*4 + reg;
      int rq = rsi[row];
      float mx = -3e38f;
#pragma unroll
      for (int j = 0; j < 2; ++j) {
        int gkey = kc*CHUNK + (2*w + j)*16 + lr;
        float v = acc[m][j][reg] * 0.125f;
        if (gkey > rq) v = -3e38f;
        s[m][j][reg] = v;
        mx = fmaxf(mx, v);
      }
#pragma unroll
      for (int o = 1; o < 16; o <<= 1) mx = fmaxf(mx, __shfl_xor(mx, o));
      rmax[m][reg] = mx;
    }
  if (lr == 0) {
#pragma unroll
    for (int m = 0; m < 3; ++m)
#pragma unroll
      for (int reg = 0; reg < 4; ++reg)
        wred[w][m*16 + hk*4 + reg] = rmax[m][reg];
  }
  __syncthreads();

  float rsum[3][4];
#pragma unroll
  for (int m = 0; m < 3; ++m)
#pragma unroll
    for (int reg = 0; reg < 4; ++reg) {
      int row = m*16 + hk*4 + reg;
      float gm = fmaxf(fmaxf(wred[0][row], wred[1][row]), fmaxf(wred[2][row], wred[3][row]));
      gm = fmaxf(gm, -1e37f);
      float sum = 0.f;
#pragma unroll
      for (int j = 0; j < 2; ++j) {
        float p = __expf(s[m][j][reg] - gm);
        sum += p;
        U.ps[row][(2*w + j)*16 + lr] = f2bf(p);
      }
#pragma unroll
      for (int o = 1; o < 16; o <<= 1) sum += __shfl_xor(sum, o);
      rsum[m][reg] = sum;
      rmax[m][reg] = gm;
    }
  if (lr == 0) {
#pragma unroll
    for (int m = 0; m < 3; ++m)
#pragma unroll
      for (int reg = 0; reg < 4; ++reg)
        wsum[w][m*16 + hk*4 + reg] = rsum[m][reg];
  }
  __syncthreads();

  if (w == 0 && lr == 0) {
    size_t base = ((size_t)(b*NH + h)*NCH + kc)*KK;
#pragma unroll
    for (int m = 0; m < 3; ++m)
#pragma unroll
      for (int reg = 0; reg < 4; ++reg) {
        int row = m*16 + hk*4 + reg;
        if (row < KK) {
          float L = wsum[0][row] + wsum[1][row] + wsum[2][row] + wsum[3][row];
          mpart[base + row] = rmax[m][reg];
          lpart[base + row] = L;
        }
      }
  }

  f32x4 acc2[3] = {};
#pragma unroll
  for (int kt = 0; kt < 4; ++kt) {
    short8 bv = *(const short8*)&Vt[w*16 + lr][kt*32 + hk*8];
#pragma unroll
    for (int m = 0; m < 3; ++m) {
      short8 av = *(const short8*)&U.ps[m*16 + lr][kt*32 + hk*8];
      acc2[m] = __builtin_amdgcn_mfma_f32_16x16x32_bf16(av, bv, acc2[m], 0, 0, 0);
    }
  }
  size_t obase = (((size_t)(b*NH + h)*NCH + kc)*KK)*HD;
#pragma unroll
  for (int m = 0; m < 3; ++m)
#pragma unroll
    for (int reg = 0; reg < 4; ++reg) {
      int q = m*16 + hk*4 + reg;
      if (q < KK) Opart[obase + (size_t)q*HD + w*16 + lr] = acc2[m][reg];
    }
}

__global__ __launch_bounds__(64) void attn_combine_kernel(
    const float* __restrict__ Opart,
    const float* __restrict__ mpart,
    const float* __restrict__ lpart,
    unsigned short* __restrict__ ctxg)
{
  int h = blockIdx.x, j = blockIdx.y;
  int b = j / KK, q = j % KK;
  int d = threadIdx.x;
  size_t mb = (size_t)(b*NH + h)*NCH;
  float M = -3e38f;
#pragma unroll
  for (int c = 0; c < NCH; ++c) M = fmaxf(M, mpart[(mb + c)*KK + q]);
  float L = 0.f, o = 0.f;
#pragma unroll
  for (int c = 0; c < NCH; ++c) {
    float f = __expf(mpart[(mb + c)*KK + q] - M);
    L += lpart[(mb + c)*KK + q] * f;
    o = fmaf(Opart[((mb + c)*KK + q)*HD + d], f, o);
  }
  ctxg[(size_t)j*DIM + h*HD + d] = f2bf(o / L);
}

// out[selrow] = x[selrow] + (sum_sk apart[sk][j] + out_b) * sel[selrow].
__global__ void rowfix_kernel(const float* __restrict__ x,
                              const float* __restrict__ apart,
                              const float* __restrict__ out_b,
                              const float* __restrict__ sel,
                              const int* __restrict__ idx,
                              float* __restrict__ out)
{
  int j = blockIdx.x;           // 0..NSEL-1
  int b = j / KK;
  int r = idx[j];
  int col = threadIdx.x * 4;
  size_t off = ((size_t)(b * SEQ + r)) * DIM + col;
  float s = sel[b * SEQ + r];
  float4 a = *(const float4*)(out_b + col);
#pragma unroll
  for (int sk = 0; sk < SPLITK; ++sk) {
    float4 p = *(const float4*)(apart + ((size_t)sk * MPAD + j) * DIM + col);
    a.x += p.x; a.y += p.y; a.z += p.z; a.w += p.w;
  }
  float4 v = *(const float4*)(x + off);
  v.x += a.x * s; v.y += a.y * s; v.z += a.z * s; v.w += a.w * s;
  *(float4*)(out + off) = v;
}

extern "C" void kernel_launch(void* const* d_in, const int* in_sizes, int n_in,
                              void* d_out, int out_size, void* d_ws, size_t ws_size,
                              hipStream_t stream)
{
  (void)in_sizes; (void)n_in; (void)out_size; (void)ws_size;
  const float* x      = (const float*)d_in[0];
  const float* Wqkv_w = (const float*)d_in[1];
  const float* Wqkv_b = (const float*)d_in[2];
  const float* sel_w  = (const float*)d_in[3];
  const float* sel_b  = (const float*)d_in[4];
  const float* out_w  = (const float*)d_in[5];
  const float* out_b  = (const float*)d_in[6];
  float* out = (float*)d_out;
  char* ws = (char*)d_ws;

  unsigned short* xb    = (unsigned short*)(ws);                        // 8 MB
  unsigned short* wqkvb = (unsigned short*)(ws + (8u  << 20));          // 6 MB
  unsigned short* outwb = (unsigned short*)(ws + (14u << 20));          // 2 MB
  unsigned short* kvb   = (unsigned short*)(ws + (16u << 20));          // 16 MB
  float* z      = (float*)(ws + (32u << 20));                           // 16 KB
  float* sel    = (float*)(ws + (32u << 20) + (16u << 10));             // 16 KB
  int*   idx    = (int*)  (ws + (32u << 20) + (32u << 10));             // ~1 KB
  unsigned short* ctxg = (unsigned short*)(ws + (33u << 20) + (256u << 10)); // 256 KB
  float* Opart = (float*)(ws + (35u << 20));                            // 6.0 MB
  float* mpart = (float*)(ws + (42u << 20));                            // 94 KB
  float* lpart = (float*)(ws + (42u << 20) + (256u << 10));             // 94 KB
  float* qpart = (float*)(ws + (44u << 20));                            // 4 MB
  float* apart = (float*)(ws + (48u << 20));                            // 4 MB

  prep_kernel<<<3072, 256, 0, stream>>>(Wqkv_w, out_w, wqkvb, outwb,
                                        x, xb, sel_w, sel_b, z, out);
  topk_kernel<<<BATCH, 256, 0, stream>>>(z, sel, idx);

  gemms_kernel<<<576, 256, 0, stream>>>(xb, wqkvb, Wqkv_b, kvb, qpart, idx);

  dim3 gac(NH, BATCH, NCH);
  attn_chunk_kernel<<<gac, 256, 0, stream>>>(qpart, Wqkv_b, kvb, idx, Opart, mpart, lpart);
  dim3 gcb(NH, NSEL);
  attn_combine_kernel<<<gcb, 64, 0, stream>>>(Opart, mpart, lpart, ctxg);

  dim3 gsk(DIM/128, 1, SPLITK);
  gemm_splitk_kernel<<<gsk, 256, 0, stream>>>(ctxg, outwb, apart, DIM, DIM);

  rowfix_kernel<<<NSEL, 256, 0, stream>>>(x, apart, out_b, sel, idx, out);
}